// Round 4
// baseline (273.121 us; speedup 1.0000x reference)
//
#include <hip/hip_runtime.h>
#include <hip/hip_bf16.h>

#define NN 50000
#define NE 800000
#define PAD 64          // slots per node; P(deg>=64) ~ 0 for Poisson(16)
#define CAB 196         // ca/cb sub-blocks inside role-3
#define NBK 391         // coarse buckets of 128 nodes (391*128 = 50048 >= NN)
#define CAPB 2560       // per-bucket edge capacity (mean 2048, +11 sigma)
#define GB_STRIDE 32    // gbase padded 1 counter / 128B line
#define NCHUNK 1563     // ceil(NN/32) node-chunks of 32 for attn kernels
#define NPAIR 782       // ceil(NCHUNK/2)

typedef _Float16 fp16x8 __attribute__((ext_vector_type(8)));
typedef _Float16 half2 __attribute__((ext_vector_type(2)));
typedef __attribute__((ext_vector_type(8))) unsigned short ushort8;  // 16 B
typedef __attribute__((ext_vector_type(4))) float f32x4;
// ext-vector types for __builtin_nontemporal_* (struct types not accepted)
typedef __attribute__((ext_vector_type(2))) unsigned int   u32x2;
typedef __attribute__((ext_vector_type(4))) unsigned short u16x4;

static __device__ __forceinline__ unsigned short f2h(float x) {
    _Float16 h = (_Float16)x;                              // v_cvt_f16_f32 (RNE)
    return __builtin_bit_cast(unsigned short, h);
}
static __device__ __forceinline__ float dot2(half2 a, half2 b, float c) {
#if __has_builtin(__builtin_amdgcn_fdot2)
    return __builtin_amdgcn_fdot2(a, b, c, false);         // v_dot2_f32_f16
#else
    return c + (float)a.x * (float)b.x + (float)a.y * (float)b.y;
#endif
}
static __device__ __forceinline__ half2 h2(unsigned u) {
    return __builtin_bit_cast(half2, u);
}

// ---------------------------------------------------------------------------
// Kernel 1 (fused): QKV GEMM + RPE constants + COARSE edge bucketing.
// Unchanged from r3 (head-major kh/vh epilogue).
// ---------------------------------------------------------------------------
__global__ __launch_bounds__(256) void qkv_gemm(
    const float* __restrict__ feat, const float* __restrict__ w,
    const float* __restrict__ bias, unsigned short* __restrict__ qbuf16,
    unsigned short* __restrict__ kh, unsigned short* __restrict__ vh,
    const float* __restrict__ coord, const float* __restrict__ rpe_w,
    const float* __restrict__ rpe_b, float* __restrict__ ca,
    float* __restrict__ cb,
    const int* __restrict__ graph, unsigned int* __restrict__ gbase,
    unsigned int* __restrict__ ebuf)
{
    const int t    = threadIdx.x;
    const int role = blockIdx.x & 3;
    const int bi   = blockIdx.x >> 2;      // 0..390

    __shared__ __align__(16) unsigned short Ah[128][40];   // 10 KB
    __shared__ __align__(16) unsigned short Bh[128][40];   // 10 KB

    if (role == 3) {                       // aux path (block-uniform branches only)
        unsigned int* hist  = (unsigned int*)&Ah[0][0];    // [512] used: 0..390
        unsigned int* sbase = hist + 512;                  // [512] used: 0..390
        for (int u = t; u < NBK; u += 256) hist[u] = 0u;
        __syncthreads();

        int dsts[8], srcs[8];
        bool ok[8];
        const int e0 = bi * 2048;
#pragma unroll
        for (int u = 0; u < 8; ++u) {
            int e = e0 + u * 256 + t;
            ok[u] = (e < NE);
            if (ok[u]) { dsts[u] = graph[e]; srcs[u] = graph[NE + e]; }
        }
#pragma unroll
        for (int u = 0; u < 8; ++u)
            if (ok[u]) atomicAdd(&hist[dsts[u] >> 7], 1u); // LDS atomic
        __syncthreads();
        for (int u = t; u < NBK; u += 256) {
            unsigned int c = hist[u];
            unsigned int s = c ? atomicAdd(&gbase[u * GB_STRIDE], c) : 0u;  // padded global
            sbase[u] = s;
            hist[u]  = 0u;                                 // reuse as local rank
        }
        __syncthreads();
#pragma unroll
        for (int u = 0; u < 8; ++u)
            if (ok[u]) {
                int b = dsts[u] >> 7;
                unsigned int pos = sbase[b] + atomicAdd(&hist[b], 1u);
                if (pos < CAPB)
                    ebuf[(size_t)b * CAPB + pos] =
                        ((unsigned int)(dsts[u] & 127) << 16) | (unsigned int)srcs[u];
            }

        if (bi < CAB) {
            __shared__ float s_rw[12];
            __shared__ float s_rb[4];
            if (t < 12) {
                int h = t / 3, p = t % 3;
                float s = 0.f;
                for (int d = 0; d < 32; ++d) s += rpe_w[(h * 32 + d) * 3 + p];
                s_rw[t] = s;
            } else if (t < 16) {
                int h = t - 12;
                float s = 0.f;
                for (int d = 0; d < 32; ++d) s += rpe_b[h * 32 + d];
                s_rb[h] = s;
            }
            __syncthreads();
            int n = bi * 256 + t;
            if (n < NN) {
                float c0 = coord[n * 3 + 0], c1 = coord[n * 3 + 1], c2 = coord[n * 3 + 2];
#pragma unroll
                for (int h = 0; h < 4; ++h) {
                    float a = c0 * s_rw[h * 3 + 0] + c1 * s_rw[h * 3 + 1] + c2 * s_rw[h * 3 + 2];
                    ca[n * 4 + h] = a;
                    cb[n * 4 + h] = a + s_rb[h];
                }
            }
        }
        return;
    }

    const int bm = bi * 128;
    const int bc = role * 128;             // 0=q 1=k 2=v

    const int wave = t >> 6;
    const int lane = t & 63;
    const int wr = wave & 1;
    const int wc = wave >> 1;
    const int qd = lane >> 4;
    const int l15 = lane & 15;

    f32x4 acc[4][4];
#pragma unroll
    for (int i = 0; i < 4; ++i)
#pragma unroll
        for (int j = 0; j < 4; ++j)
            acc[i][j] = (f32x4){0.f, 0.f, 0.f, 0.f};

    for (int ks = 0; ks < 4; ++ks) {
        const int k0 = ks * 32;
        if (ks) __syncthreads();
#pragma unroll
        for (int c = 0; c < 2; ++c) {
            int idx = c * 256 + t;          // 0..511
            int r  = idx >> 2;
            int c8 = (idx & 3) * 8;
            int ga = bm + r;
            ushort8 a8 = (ushort8){0,0,0,0,0,0,0,0};
            if (ga < NN) {
                const float* ap = feat + (size_t)ga * 128 + k0 + c8;
                float4 x = *(const float4*)ap;
                float4 y = *(const float4*)(ap + 4);
                a8 = (ushort8){f2h(x.x), f2h(x.y), f2h(x.z), f2h(x.w),
                               f2h(y.x), f2h(y.y), f2h(y.z), f2h(y.w)};
            }
            *(ushort8*)&Ah[r][c8] = a8;
            const float* bp = w + (size_t)(bc + r) * 128 + k0 + c8;
            float4 bx = *(const float4*)bp;
            float4 by = *(const float4*)(bp + 4);
            *(ushort8*)&Bh[r][c8] = (ushort8){f2h(bx.x), f2h(bx.y), f2h(bx.z), f2h(bx.w),
                                              f2h(by.x), f2h(by.y), f2h(by.z), f2h(by.w)};
        }
        __syncthreads();
        fp16x8 af[4];
#pragma unroll
        for (int i = 0; i < 4; ++i)
            af[i] = *(const fp16x8*)&Ah[wr * 64 + 16 * i + l15][qd * 8];
#pragma unroll
        for (int j = 0; j < 4; ++j) {
            fp16x8 bf = *(const fp16x8*)&Bh[wc * 64 + 16 * j + l15][qd * 8];
#pragma unroll
            for (int i = 0; i < 4; ++i)
                acc[i][j] = __builtin_amdgcn_mfma_f32_16x16x32_f16(af[i], bf, acc[i][j], 0, 0, 0);
        }
    }

    float bj[4];
#pragma unroll
    for (int j = 0; j < 4; ++j)
        bj[j] = bias[bc + wc * 64 + 16 * j + l15];

    unsigned short* Ct = &Ah[0][0];        // Ct[32][136] fp16, overlays Ah
    const int isQ = (role == 0);
    unsigned short* kv_dst = (role == 1) ? kh : vh;
    const int relRowW = wr * 16 + qd * 4;

    for (int i = 0; i < 4; ++i) {
        __syncthreads();
#pragma unroll
        for (int j = 0; j < 4; ++j) {
            int col = wc * 64 + 16 * j + l15;
#pragma unroll
            for (int rg = 0; rg < 4; ++rg)
                Ct[(relRowW + rg) * 136 + col] = f2h(acc[i][j][rg] + bj[j]);
        }
        __syncthreads();
#pragma unroll
        for (int p = 0; p < 2; ++p) {
            int linear = p * 256 + t;
            int rr = linear >> 4;          // 0..31
            int cc = linear & 15;          // 16B chunk (8 cols)
            int absRow = bm + 16 * i + rr + ((rr >> 4) * 48);
            if (absRow < NN) {
                ushort8 val = *(const ushort8*)&Ct[rr * 136 + cc * 8];
                if (isQ) {
                    *(ushort8*)(qbuf16 + (size_t)absRow * 128 + cc * 8) = val;
                } else {
                    size_t off = (size_t)(cc >> 2) * NN * 32 + (size_t)absRow * 32 + (cc & 3) * 8;
                    *(ushort8*)(kv_dst + off) = val;
                }
            }
        }
    }
}

// ---------------------------------------------------------------------------
// Kernel 1.5: bucket regions -> exact padded CSR (unchanged).
// ---------------------------------------------------------------------------
__global__ __launch_bounds__(256) void bucket_to_csr(
    const unsigned int* __restrict__ gbase, const unsigned int* __restrict__ ebuf,
    int* __restrict__ cnt, unsigned short* __restrict__ sorted_src)
{
    __shared__ unsigned int ncnt[128];
    const int b = blockIdx.x;
    const int t = threadIdx.x;
    if (t < 128) ncnt[t] = 0u;
    __syncthreads();

    int total = (int)gbase[b * GB_STRIDE];
    if (total > CAPB) total = CAPB;
    const unsigned int* eb = ebuf + (size_t)b * CAPB;
    for (int i = t; i < total; i += 256) {
        unsigned int e = eb[i];
        int dl = (int)(e >> 16);                           // 0..127
        unsigned int slot = atomicAdd(&ncnt[dl], 1u);      // LDS atomic
        if (slot < PAD)
            sorted_src[(((size_t)(b * 128 + dl)) << 6) + slot] =
                (unsigned short)(e & 0xFFFFu);
    }
    __syncthreads();
    if (t < 128) {
        int node = b * 128 + t;
        if (node < NN) {
            unsigned int c = ncnt[t];
            cnt[node] = (c > PAD) ? PAD : (int)c;
        }
    }
}

// ---------------------------------------------------------------------------
// Phase A: attention scores. Head-partitioned (head h on XCDs {2h,2h+1},
// whose 4MB L2 holds the 3.2MB kh[h] table). CHANGES vs r3 (which showed
// FETCH 136MB = kh thrashed out of L2):
//  - ALL streaming operands (q, ss, cnt, cb) use nontemporal loads; e and
//    invden use nontemporal stores -> only kh + ca allocate in L2.
//  - e rows buffered in LDS and dumped as full-line float4 stores once per
//    block (r3 wrote 16B partial lines -> 40MB WRITE amplification).
// ---------------------------------------------------------------------------
__global__ __launch_bounds__(256) void attn_score(
    const unsigned short* __restrict__ qbuf16, const unsigned short* __restrict__ kh,
    const float* __restrict__ ca, const float* __restrict__ cb,
    const int* __restrict__ cnt, const unsigned short* __restrict__ sorted_src,
    float* __restrict__ ebufE, float* __restrict__ invden)
{
    __shared__ float eL[32][64];           // 8 KB e-staging
    __shared__ int   dL[32];

    const int t = threadIdx.x;
    const int x = blockIdx.x & 7;
    const int h = x >> 1;
    const int chunk = (blockIdx.x >> 3) * 2 + (x & 1);
    const int r = t >> 3;                  // row in chunk 0..31
    const int n = chunk * 32 + r;
    const int l  = t & 7;
    const int l4 = l * 4;
    const bool act = (n < NN);

    int d = 0;
    if (act) d = __builtin_nontemporal_load(cnt + n);
    if (l == 0) dL[r] = act ? d : 0;

    if (act) {
        const u32x2 qv = __builtin_nontemporal_load(
            (const u32x2*)(qbuf16 + (size_t)n * 128 + h * 32 + l4));
        const half2 q01 = h2(qv.x), q23 = h2(qv.y);
        const float cbh = __builtin_nontemporal_load(cb + n * 4 + h);
        const unsigned short* sl  = sorted_src + ((size_t)n << 6);
        const unsigned short* khp = kh + (size_t)h * NN * 32;

        float den = 0.f;
        int i = 0;
        for (; i + 3 < d; i += 4) {
            u16x4 s4 = __builtin_nontemporal_load((const u16x4*)(sl + i));
            uint2 kk[4];
            float aa[4];
            kk[0] = *(const uint2*)(khp + (size_t)s4.x * 32 + l4);
            kk[1] = *(const uint2*)(khp + (size_t)s4.y * 32 + l4);
            kk[2] = *(const uint2*)(khp + (size_t)s4.z * 32 + l4);
            kk[3] = *(const uint2*)(khp + (size_t)s4.w * 32 + l4);
            aa[0] = ca[(int)s4.x * 4 + h];
            aa[1] = ca[(int)s4.y * 4 + h];
            aa[2] = ca[(int)s4.z * 4 + h];
            aa[3] = ca[(int)s4.w * 4 + h];
            float p[4];
#pragma unroll
            for (int u = 0; u < 4; ++u)
                p[u] = dot2(q01, h2(kk[u].x), dot2(q23, h2(kk[u].y), 0.f));
#pragma unroll
            for (int u = 0; u < 4; ++u) {
                p[u] += __shfl_xor(p[u], 1);
                p[u] += __shfl_xor(p[u], 2);
                p[u] += __shfl_xor(p[u], 4);
            }
            float e[4];
#pragma unroll
            for (int u = 0; u < 4; ++u) { e[u] = __expf(p[u] + cbh - aa[u]); den += e[u]; }
            if (l == 0) *(f32x4*)&eL[r][i] = (f32x4){e[0], e[1], e[2], e[3]};
        }
        for (; i < d; ++i) {
            unsigned s = __builtin_nontemporal_load(sl + i);
            uint2 k0 = *(const uint2*)(khp + (size_t)s * 32 + l4);
            float a0 = ca[(int)s * 4 + h];
            float p0 = dot2(q01, h2(k0.x), dot2(q23, h2(k0.y), 0.f));
            p0 += __shfl_xor(p0, 1);
            p0 += __shfl_xor(p0, 2);
            p0 += __shfl_xor(p0, 4);
            float e = __expf(p0 + cbh - a0);
            den += e;
            if (l == 0) eL[r][i] = e;
        }
        if (l == 0)
            __builtin_nontemporal_store((den > 0.f) ? 1.0f / den : 0.f,
                                        invden + n * 4 + h);
    }

    __syncthreads();
    // dump full-line e rows: 32 rows x 16 float4 = 512 stores over 2 passes
#pragma unroll
    for (int p = 0; p < 2; ++p) {
        int idx = p * 256 + t;
        int rr = idx >> 4, c4 = idx & 15;
        int n2 = chunk * 32 + rr;
        if (n2 < NN && c4 * 4 < dL[rr]) {
            f32x4 val = *(const f32x4*)&eL[rr][c4 * 4];
            __builtin_nontemporal_store(val,
                (f32x4*)(ebufE + ((size_t)h * NN + n2) * 64 + c4 * 4));
        }
    }
}

// ---------------------------------------------------------------------------
// Phase B: weighted value sum. Same head->XCD mapping (vh[h] L2-resident);
// everything except vh is nontemporal.
// ---------------------------------------------------------------------------
__global__ __launch_bounds__(256) void attn_out(
    const unsigned short* __restrict__ vh,
    const int* __restrict__ cnt, const unsigned short* __restrict__ sorted_src,
    const float* __restrict__ ebufE, const float* __restrict__ invden,
    float* __restrict__ out)
{
    const int t = threadIdx.x;
    const int x = blockIdx.x & 7;
    const int h = x >> 1;
    const int chunk = (blockIdx.x >> 3) * 2 + (x & 1);
    const int n = chunk * 32 + (t >> 3);
    if (n >= NN) return;
    const int l  = t & 7;
    const int l4 = l * 4;

    const unsigned short* sl  = sorted_src + ((size_t)n << 6);
    const unsigned short* vhp = vh + (size_t)h * NN * 32;
    const float* erow = ebufE + ((size_t)h * NN + n) * 64;
    const int d = __builtin_nontemporal_load(cnt + n);

    float4 acc = make_float4(0.f, 0.f, 0.f, 0.f);
    int i = 0;
    for (; i + 3 < d; i += 4) {
        u16x4 s4 = __builtin_nontemporal_load((const u16x4*)(sl + i));
        f32x4 ef = __builtin_nontemporal_load((const f32x4*)(erow + i));
        uint2 vv[4];
        vv[0] = *(const uint2*)(vhp + (size_t)s4.x * 32 + l4);
        vv[1] = *(const uint2*)(vhp + (size_t)s4.y * 32 + l4);
        vv[2] = *(const uint2*)(vhp + (size_t)s4.z * 32 + l4);
        vv[3] = *(const uint2*)(vhp + (size_t)s4.w * 32 + l4);
        float ee[4] = {ef.x, ef.y, ef.z, ef.w};
#pragma unroll
        for (int u = 0; u < 4; ++u) {
            half2 a = h2(vv[u].x), b = h2(vv[u].y);
            acc.x += ee[u] * (float)a.x;
            acc.y += ee[u] * (float)a.y;
            acc.z += ee[u] * (float)b.x;
            acc.w += ee[u] * (float)b.y;
        }
    }
    for (; i < d; ++i) {
        unsigned s = __builtin_nontemporal_load(sl + i);
        float e = __builtin_nontemporal_load(erow + i);
        uint2 v0 = *(const uint2*)(vhp + (size_t)s * 32 + l4);
        half2 a = h2(v0.x), b = h2(v0.y);
        acc.x += e * (float)a.x;
        acc.y += e * (float)a.y;
        acc.z += e * (float)b.x;
        acc.w += e * (float)b.y;
    }

    const float inv = __builtin_nontemporal_load(invden + n * 4 + h);
    f32x4 o = (f32x4){acc.x * inv, acc.y * inv, acc.z * inv, acc.w * inv};
    __builtin_nontemporal_store(o, (f32x4*)(out + (size_t)n * 128 + h * 32 + l4));
}

extern "C" void kernel_launch(void* const* d_in, const int* in_sizes, int n_in,
                              void* d_out, int out_size, void* d_ws, size_t ws_size,
                              hipStream_t stream) {
    const float* feat  = (const float*)d_in[0];
    const float* coord = (const float*)d_in[1];
    const int*   graph = (const int*)d_in[2];
    const float* qkv_w = (const float*)d_in[3];
    const float* qkv_b = (const float*)d_in[4];
    const float* rpe_w = (const float*)d_in[5];
    const float* rpe_b = (const float*)d_in[6];
    float* out = (float*)d_out;

    unsigned short* qbuf16 = (unsigned short*)d_ws;                       // NN x 128 f16   (12.8 MB)
    unsigned short* kh     = qbuf16 + (size_t)NN * 128;                   // 4 x NN x 32 f16(12.8 MB)
    unsigned short* vh     = kh + (size_t)NN * 128;                       // 4 x NN x 32 f16(12.8 MB)
    int*            cnt    = (int*)(vh + (size_t)NN * 128);               // NN             (0.2 MB)
    unsigned short* sorted_src = (unsigned short*)(cnt + NN);             // NN x 64 u16    (6.4 MB)
    float* ca = (float*)(sorted_src + (size_t)NN * PAD);                  // NN x 4         (0.8 MB)
    float* cb = ca + (size_t)NN * 4;                                      // NN x 4         (0.8 MB)
    unsigned int* gbase = (unsigned int*)(cb + (size_t)NN * 4);           // NBK x 32       (50 KB)
    unsigned int* ebuf  = gbase + (size_t)NBK * GB_STRIDE;                // NBK x CAPB     (4.0 MB)
    float* ebufE  = (float*)(ebuf + (size_t)NBK * CAPB);                  // 4 x NN x 64 f32(51.2 MB)
    float* invden = ebufE + (size_t)4 * NN * 64;                          // NN x 4         (0.8 MB)

    hipMemsetAsync(gbase, 0, (size_t)NBK * GB_STRIDE * sizeof(unsigned int), stream);

    qkv_gemm <<<dim3(391 * 4), 256, 0, stream>>>(feat, qkv_w, qkv_b, qbuf16, kh, vh,
                                                 coord, rpe_w, rpe_b, ca, cb,
                                                 graph, gbase, ebuf);
    bucket_to_csr<<<dim3(NBK), 256, 0, stream>>>(gbase, ebuf, cnt, sorted_src);
    attn_score<<<dim3(NPAIR * 8), 256, 0, stream>>>(qbuf16, kh, ca, cb,
                                                    cnt, sorted_src, ebufE, invden);
    attn_out  <<<dim3(NPAIR * 8), 256, 0, stream>>>(vh, cnt, sorted_src,
                                                    ebufE, invden, out);
}

// Round 5
// 241.025 us; speedup vs baseline: 1.1332x; 1.1332x over previous
//
#include <hip/hip_runtime.h>
#include <hip/hip_bf16.h>

#define NN 50000
#define NE 800000
#define PAD 64          // slots per node; P(deg>=64) ~ 0 for Poisson(16)
#define CAB 196         // ca/cb sub-blocks inside role-3
#define NBK 391         // coarse buckets of 128 nodes (391*128 = 50048 >= NN)
#define CAPB 2560       // per-bucket edge capacity (mean 2048, +11 sigma)
#define GB_STRIDE 32    // gbase padded 1 counter / 128B line
#define NCHUNK 1563     // ceil(NN/32) node-chunks of 32 for attn kernels
#define NUNITS (4 * NCHUNK)   // (head, chunk) work units

typedef _Float16 fp16x8 __attribute__((ext_vector_type(8)));
typedef _Float16 half2 __attribute__((ext_vector_type(2)));
typedef __attribute__((ext_vector_type(8))) unsigned short ushort8;  // 16 B
typedef __attribute__((ext_vector_type(4))) float f32x4;

static __device__ __forceinline__ unsigned short f2h(float x) {
    _Float16 h = (_Float16)x;                              // v_cvt_f16_f32 (RNE)
    return __builtin_bit_cast(unsigned short, h);
}
static __device__ __forceinline__ float dot2(half2 a, half2 b, float c) {
#if __has_builtin(__builtin_amdgcn_fdot2)
    return __builtin_amdgcn_fdot2(a, b, c, false);         // v_dot2_f32_f16
#else
    return c + (float)a.x * (float)b.x + (float)a.y * (float)b.y;
#endif
}
static __device__ __forceinline__ half2 h2(unsigned u) {
    return __builtin_bit_cast(half2, u);
}
// Physical XCD id (0..7). HW-verified on gfx950 (learn_hip m09).
static __device__ __forceinline__ int xcc_id() {
    int x;
    asm volatile("s_getreg_b32 %0, hwreg(HW_REG_XCC_ID)" : "=s"(x));
    return x & 7;
}
// Claim one (head, chunk) unit. Prefer head `pref`; fall through others.
// Grid == NUNITS guarantees all units are claimed exactly once.
static __device__ __forceinline__ int pop_unit(unsigned int* q, int pref, int* h_out) {
    for (int u = 0; u < 4; ++u) {
        int h = (pref + u) & 3;
        unsigned int idx = atomicAdd(&q[h * GB_STRIDE], 1u);
        if (idx < NCHUNK) { *h_out = h; return (int)idx; }
    }
    return -1;
}

// ---------------------------------------------------------------------------
// Kernel 1 (fused): QKV GEMM + RPE constants + COARSE edge bucketing.
// Unchanged from r3/r4 (head-major kh/vh epilogue).
// ---------------------------------------------------------------------------
__global__ __launch_bounds__(256) void qkv_gemm(
    const float* __restrict__ feat, const float* __restrict__ w,
    const float* __restrict__ bias, unsigned short* __restrict__ qbuf16,
    unsigned short* __restrict__ kh, unsigned short* __restrict__ vh,
    const float* __restrict__ coord, const float* __restrict__ rpe_w,
    const float* __restrict__ rpe_b, float* __restrict__ ca,
    float* __restrict__ cb,
    const int* __restrict__ graph, unsigned int* __restrict__ gbase,
    unsigned int* __restrict__ ebuf)
{
    const int t    = threadIdx.x;
    const int role = blockIdx.x & 3;
    const int bi   = blockIdx.x >> 2;      // 0..390

    __shared__ __align__(16) unsigned short Ah[128][40];   // 10 KB
    __shared__ __align__(16) unsigned short Bh[128][40];   // 10 KB

    if (role == 3) {                       // aux path (block-uniform branches only)
        unsigned int* hist  = (unsigned int*)&Ah[0][0];    // [512] used: 0..390
        unsigned int* sbase = hist + 512;                  // [512] used: 0..390
        for (int u = t; u < NBK; u += 256) hist[u] = 0u;
        __syncthreads();

        int dsts[8], srcs[8];
        bool ok[8];
        const int e0 = bi * 2048;
#pragma unroll
        for (int u = 0; u < 8; ++u) {
            int e = e0 + u * 256 + t;
            ok[u] = (e < NE);
            if (ok[u]) { dsts[u] = graph[e]; srcs[u] = graph[NE + e]; }
        }
#pragma unroll
        for (int u = 0; u < 8; ++u)
            if (ok[u]) atomicAdd(&hist[dsts[u] >> 7], 1u); // LDS atomic
        __syncthreads();
        for (int u = t; u < NBK; u += 256) {
            unsigned int c = hist[u];
            unsigned int s = c ? atomicAdd(&gbase[u * GB_STRIDE], c) : 0u;  // padded global
            sbase[u] = s;
            hist[u]  = 0u;                                 // reuse as local rank
        }
        __syncthreads();
#pragma unroll
        for (int u = 0; u < 8; ++u)
            if (ok[u]) {
                int b = dsts[u] >> 7;
                unsigned int pos = sbase[b] + atomicAdd(&hist[b], 1u);
                if (pos < CAPB)
                    ebuf[(size_t)b * CAPB + pos] =
                        ((unsigned int)(dsts[u] & 127) << 16) | (unsigned int)srcs[u];
            }

        if (bi < CAB) {
            __shared__ float s_rw[12];
            __shared__ float s_rb[4];
            if (t < 12) {
                int h = t / 3, p = t % 3;
                float s = 0.f;
                for (int d = 0; d < 32; ++d) s += rpe_w[(h * 32 + d) * 3 + p];
                s_rw[t] = s;
            } else if (t < 16) {
                int h = t - 12;
                float s = 0.f;
                for (int d = 0; d < 32; ++d) s += rpe_b[h * 32 + d];
                s_rb[h] = s;
            }
            __syncthreads();
            int n = bi * 256 + t;
            if (n < NN) {
                float c0 = coord[n * 3 + 0], c1 = coord[n * 3 + 1], c2 = coord[n * 3 + 2];
#pragma unroll
                for (int h = 0; h < 4; ++h) {
                    float a = c0 * s_rw[h * 3 + 0] + c1 * s_rw[h * 3 + 1] + c2 * s_rw[h * 3 + 2];
                    ca[n * 4 + h] = a;
                    cb[n * 4 + h] = a + s_rb[h];
                }
            }
        }
        return;
    }

    const int bm = bi * 128;
    const int bc = role * 128;             // 0=q 1=k 2=v

    const int wave = t >> 6;
    const int lane = t & 63;
    const int wr = wave & 1;
    const int wc = wave >> 1;
    const int qd = lane >> 4;
    const int l15 = lane & 15;

    f32x4 acc[4][4];
#pragma unroll
    for (int i = 0; i < 4; ++i)
#pragma unroll
        for (int j = 0; j < 4; ++j)
            acc[i][j] = (f32x4){0.f, 0.f, 0.f, 0.f};

    for (int ks = 0; ks < 4; ++ks) {
        const int k0 = ks * 32;
        if (ks) __syncthreads();
#pragma unroll
        for (int c = 0; c < 2; ++c) {
            int idx = c * 256 + t;          // 0..511
            int r  = idx >> 2;
            int c8 = (idx & 3) * 8;
            int ga = bm + r;
            ushort8 a8 = (ushort8){0,0,0,0,0,0,0,0};
            if (ga < NN) {
                const float* ap = feat + (size_t)ga * 128 + k0 + c8;
                float4 x = *(const float4*)ap;
                float4 y = *(const float4*)(ap + 4);
                a8 = (ushort8){f2h(x.x), f2h(x.y), f2h(x.z), f2h(x.w),
                               f2h(y.x), f2h(y.y), f2h(y.z), f2h(y.w)};
            }
            *(ushort8*)&Ah[r][c8] = a8;
            const float* bp = w + (size_t)(bc + r) * 128 + k0 + c8;
            float4 bx = *(const float4*)bp;
            float4 by = *(const float4*)(bp + 4);
            *(ushort8*)&Bh[r][c8] = (ushort8){f2h(bx.x), f2h(bx.y), f2h(bx.z), f2h(bx.w),
                                              f2h(by.x), f2h(by.y), f2h(by.z), f2h(by.w)};
        }
        __syncthreads();
        fp16x8 af[4];
#pragma unroll
        for (int i = 0; i < 4; ++i)
            af[i] = *(const fp16x8*)&Ah[wr * 64 + 16 * i + l15][qd * 8];
#pragma unroll
        for (int j = 0; j < 4; ++j) {
            fp16x8 bf = *(const fp16x8*)&Bh[wc * 64 + 16 * j + l15][qd * 8];
#pragma unroll
            for (int i = 0; i < 4; ++i)
                acc[i][j] = __builtin_amdgcn_mfma_f32_16x16x32_f16(af[i], bf, acc[i][j], 0, 0, 0);
        }
    }

    float bj[4];
#pragma unroll
    for (int j = 0; j < 4; ++j)
        bj[j] = bias[bc + wc * 64 + 16 * j + l15];

    unsigned short* Ct = &Ah[0][0];        // Ct[32][136] fp16, overlays Ah
    const int isQ = (role == 0);
    unsigned short* kv_dst = (role == 1) ? kh : vh;
    const int relRowW = wr * 16 + qd * 4;

    for (int i = 0; i < 4; ++i) {
        __syncthreads();
#pragma unroll
        for (int j = 0; j < 4; ++j) {
            int col = wc * 64 + 16 * j + l15;
#pragma unroll
            for (int rg = 0; rg < 4; ++rg)
                Ct[(relRowW + rg) * 136 + col] = f2h(acc[i][j][rg] + bj[j]);
        }
        __syncthreads();
#pragma unroll
        for (int p = 0; p < 2; ++p) {
            int linear = p * 256 + t;
            int rr = linear >> 4;          // 0..31
            int cc = linear & 15;          // 16B chunk (8 cols)
            int absRow = bm + 16 * i + rr + ((rr >> 4) * 48);
            if (absRow < NN) {
                ushort8 val = *(const ushort8*)&Ct[rr * 136 + cc * 8];
                if (isQ) {
                    *(ushort8*)(qbuf16 + (size_t)absRow * 128 + cc * 8) = val;
                } else {
                    size_t off = (size_t)(cc >> 2) * NN * 32 + (size_t)absRow * 32 + (cc & 3) * 8;
                    *(ushort8*)(kv_dst + off) = val;
                }
            }
        }
    }
}

// ---------------------------------------------------------------------------
// Kernel 1.5: bucket regions -> exact padded CSR (unchanged).
// ---------------------------------------------------------------------------
__global__ __launch_bounds__(256) void bucket_to_csr(
    const unsigned int* __restrict__ gbase, const unsigned int* __restrict__ ebuf,
    int* __restrict__ cnt, unsigned short* __restrict__ sorted_src)
{
    __shared__ unsigned int ncnt[128];
    const int b = blockIdx.x;
    const int t = threadIdx.x;
    if (t < 128) ncnt[t] = 0u;
    __syncthreads();

    int total = (int)gbase[b * GB_STRIDE];
    if (total > CAPB) total = CAPB;
    const unsigned int* eb = ebuf + (size_t)b * CAPB;
    for (int i = t; i < total; i += 256) {
        unsigned int e = eb[i];
        int dl = (int)(e >> 16);                           // 0..127
        unsigned int slot = atomicAdd(&ncnt[dl], 1u);      // LDS atomic
        if (slot < PAD)
            sorted_src[(((size_t)(b * 128 + dl)) << 6) + slot] =
                (unsigned short)(e & 0xFFFFu);
    }
    __syncthreads();
    if (t < 128) {
        int node = b * 128 + t;
        if (node < NN) {
            unsigned int c = ncnt[t];
            cnt[node] = (c > PAD) ? PAD : (int)c;
        }
    }
}

// ---------------------------------------------------------------------------
// Phase A: attention scores. CHANGES vs r4:
//  - head->XCD affinity via REAL XCD id (s_getreg HW_REG_XCC_ID) + per-head
//    atomic work queues (r3/r4's bx&7 guess was falsified: FETCH showed every
//    XCD touching all 4 head tables). Grid == NUNITS; queue counting
//    guarantees each (head,chunk) is processed exactly once; affinity is
//    only a locality preference.
//  - NT LOADS REVERTED (r4: 1.4 TB/s, +19us — NT bypasses L1, pure latency
//    loss). Normal cached loads for q/ss/cnt/cb/kh/ca.
//  - keep LDS e-staging + NT full-line stores (r4's real win: WRITE 40->19MB).
// ---------------------------------------------------------------------------
__global__ __launch_bounds__(256) void attn_score(
    const unsigned short* __restrict__ qbuf16, const unsigned short* __restrict__ kh,
    const float* __restrict__ ca, const float* __restrict__ cb,
    const int* __restrict__ cnt, const unsigned short* __restrict__ sorted_src,
    float* __restrict__ ebufE, float* __restrict__ invden,
    unsigned int* __restrict__ queues)
{
    __shared__ float eL[32][68];           // +4 pad: spread row starts over banks
    __shared__ int   dL[32];
    __shared__ int   unit[2];              // {h, chunk}

    const int t = threadIdx.x;
    if (t == 0) {
        int h;
        int c = pop_unit(queues, xcc_id() >> 1, &h);
        unit[0] = h; unit[1] = c;
    }
    __syncthreads();
    const int chunk = unit[1];
    if (chunk < 0) return;
    const int h = unit[0];

    const int r = t >> 3;                  // row in chunk 0..31
    const int n = chunk * 32 + r;
    const int l  = t & 7;
    const int l4 = l * 4;
    const bool act = (n < NN);

    int d = 0;
    if (act) d = cnt[n];
    if (l == 0) dL[r] = act ? d : 0;

    if (act) {
        const uint2 qv = *(const uint2*)(qbuf16 + (size_t)n * 128 + h * 32 + l4);
        const half2 q01 = h2(qv.x), q23 = h2(qv.y);
        const float cbh = cb[n * 4 + h];
        const unsigned short* sl  = sorted_src + ((size_t)n << 6);
        const unsigned short* khp = kh + (size_t)h * NN * 32;

        float den = 0.f;
        int i = 0;
        for (; i + 3 < d; i += 4) {
            ushort4 s4 = *(const ushort4*)(sl + i);
            uint2 kk[4];
            float aa[4];
            kk[0] = *(const uint2*)(khp + (size_t)s4.x * 32 + l4);
            kk[1] = *(const uint2*)(khp + (size_t)s4.y * 32 + l4);
            kk[2] = *(const uint2*)(khp + (size_t)s4.z * 32 + l4);
            kk[3] = *(const uint2*)(khp + (size_t)s4.w * 32 + l4);
            aa[0] = ca[(int)s4.x * 4 + h];
            aa[1] = ca[(int)s4.y * 4 + h];
            aa[2] = ca[(int)s4.z * 4 + h];
            aa[3] = ca[(int)s4.w * 4 + h];
            float p[4];
#pragma unroll
            for (int u = 0; u < 4; ++u)
                p[u] = dot2(q01, h2(kk[u].x), dot2(q23, h2(kk[u].y), 0.f));
#pragma unroll
            for (int u = 0; u < 4; ++u) {
                p[u] += __shfl_xor(p[u], 1);
                p[u] += __shfl_xor(p[u], 2);
                p[u] += __shfl_xor(p[u], 4);
            }
            float e[4];
#pragma unroll
            for (int u = 0; u < 4; ++u) { e[u] = __expf(p[u] + cbh - aa[u]); den += e[u]; }
            if (l == 0) *(f32x4*)&eL[r][i] = (f32x4){e[0], e[1], e[2], e[3]};
        }
        for (; i < d; ++i) {
            unsigned s = sl[i];
            uint2 k0 = *(const uint2*)(khp + (size_t)s * 32 + l4);
            float a0 = ca[(int)s * 4 + h];
            float p0 = dot2(q01, h2(k0.x), dot2(q23, h2(k0.y), 0.f));
            p0 += __shfl_xor(p0, 1);
            p0 += __shfl_xor(p0, 2);
            p0 += __shfl_xor(p0, 4);
            float e = __expf(p0 + cbh - a0);
            den += e;
            if (l == 0) eL[r][i] = e;
        }
        if (l == 0)
            __builtin_nontemporal_store((den > 0.f) ? 1.0f / den : 0.f,
                                        invden + n * 4 + h);
    }

    __syncthreads();
    // dump full-line e rows: 32 rows x 16 float4, NT (write-once stream)
#pragma unroll
    for (int p = 0; p < 2; ++p) {
        int idx = p * 256 + t;
        int rr = idx >> 4, c4 = idx & 15;
        int n2 = chunk * 32 + rr;
        if (n2 < NN && c4 * 4 < dL[rr]) {
            f32x4 val = *(const f32x4*)&eL[rr][c4 * 4];
            __builtin_nontemporal_store(val,
                (f32x4*)(ebufE + ((size_t)h * NN + n2) * 64 + c4 * 4));
        }
    }
}

// ---------------------------------------------------------------------------
// Phase B: weighted value sum. Same XCC-queue affinity (vh[h] L2-resident).
// Normal loads; NT store on out only.
// ---------------------------------------------------------------------------
__global__ __launch_bounds__(256) void attn_out(
    const unsigned short* __restrict__ vh,
    const int* __restrict__ cnt, const unsigned short* __restrict__ sorted_src,
    const float* __restrict__ ebufE, const float* __restrict__ invden,
    float* __restrict__ out, unsigned int* __restrict__ queues)
{
    __shared__ int unit[2];
    const int t = threadIdx.x;
    if (t == 0) {
        int h;
        int c = pop_unit(queues, xcc_id() >> 1, &h);
        unit[0] = h; unit[1] = c;
    }
    __syncthreads();
    const int chunk = unit[1];
    if (chunk < 0) return;
    const int h = unit[0];

    const int n = chunk * 32 + (t >> 3);
    if (n >= NN) return;
    const int l  = t & 7;
    const int l4 = l * 4;

    const unsigned short* sl  = sorted_src + ((size_t)n << 6);
    const unsigned short* vhp = vh + (size_t)h * NN * 32;
    const float* erow = ebufE + ((size_t)h * NN + n) * 64;
    const int d = cnt[n];

    float4 acc = make_float4(0.f, 0.f, 0.f, 0.f);
    int i = 0;
    for (; i + 3 < d; i += 4) {
        ushort4 s4 = *(const ushort4*)(sl + i);
        float4 ef = *(const float4*)(erow + i);
        uint2 vv[4];
        vv[0] = *(const uint2*)(vhp + (size_t)s4.x * 32 + l4);
        vv[1] = *(const uint2*)(vhp + (size_t)s4.y * 32 + l4);
        vv[2] = *(const uint2*)(vhp + (size_t)s4.z * 32 + l4);
        vv[3] = *(const uint2*)(vhp + (size_t)s4.w * 32 + l4);
        float ee[4] = {ef.x, ef.y, ef.z, ef.w};
#pragma unroll
        for (int u = 0; u < 4; ++u) {
            half2 a = h2(vv[u].x), b = h2(vv[u].y);
            acc.x += ee[u] * (float)a.x;
            acc.y += ee[u] * (float)a.y;
            acc.z += ee[u] * (float)b.x;
            acc.w += ee[u] * (float)b.y;
        }
    }
    for (; i < d; ++i) {
        unsigned s = sl[i];
        float e = erow[i];
        uint2 v0 = *(const uint2*)(vhp + (size_t)s * 32 + l4);
        half2 a = h2(v0.x), b = h2(v0.y);
        acc.x += e * (float)a.x;
        acc.y += e * (float)a.y;
        acc.z += e * (float)b.x;
        acc.w += e * (float)b.y;
    }

    const float inv = invden[n * 4 + h];
    f32x4 o = (f32x4){acc.x * inv, acc.y * inv, acc.z * inv, acc.w * inv};
    __builtin_nontemporal_store(o, (f32x4*)(out + (size_t)n * 128 + h * 32 + l4));
}

extern "C" void kernel_launch(void* const* d_in, const int* in_sizes, int n_in,
                              void* d_out, int out_size, void* d_ws, size_t ws_size,
                              hipStream_t stream) {
    const float* feat  = (const float*)d_in[0];
    const float* coord = (const float*)d_in[1];
    const int*   graph = (const int*)d_in[2];
    const float* qkv_w = (const float*)d_in[3];
    const float* qkv_b = (const float*)d_in[4];
    const float* rpe_w = (const float*)d_in[5];
    const float* rpe_b = (const float*)d_in[6];
    float* out = (float*)d_out;

    unsigned short* qbuf16 = (unsigned short*)d_ws;                       // NN x 128 f16   (12.8 MB)
    unsigned short* kh     = qbuf16 + (size_t)NN * 128;                   // 4 x NN x 32 f16(12.8 MB)
    unsigned short* vh     = kh + (size_t)NN * 128;                       // 4 x NN x 32 f16(12.8 MB)
    int*            cnt    = (int*)(vh + (size_t)NN * 128);               // NN             (0.2 MB)
    unsigned short* sorted_src = (unsigned short*)(cnt + NN);             // NN x 64 u16    (6.4 MB)
    float* ca = (float*)(sorted_src + (size_t)NN * PAD);                  // NN x 4         (0.8 MB)
    float* cb = ca + (size_t)NN * 4;                                      // NN x 4         (0.8 MB)
    unsigned int* gbase = (unsigned int*)(cb + (size_t)NN * 4);           // NBK x 32       (50 KB)
    unsigned int* qscore = gbase + (size_t)NBK * GB_STRIDE;               // 4 x 32
    unsigned int* qout   = qscore + 4 * GB_STRIDE;                        // 4 x 32
    unsigned int* ebuf  = qout + 4 * GB_STRIDE;                           // NBK x CAPB     (4.0 MB)
    float* ebufE  = (float*)(ebuf + (size_t)NBK * CAPB);                  // 4 x NN x 64 f32(51.2 MB)
    float* invden = ebufE + (size_t)4 * NN * 64;                          // NN x 4         (0.8 MB)

    // zero gbase + both queue blocks in one memset
    hipMemsetAsync(gbase, 0,
                   ((size_t)NBK * GB_STRIDE + 8 * GB_STRIDE) * sizeof(unsigned int),
                   stream);

    qkv_gemm <<<dim3(391 * 4), 256, 0, stream>>>(feat, qkv_w, qkv_b, qbuf16, kh, vh,
                                                 coord, rpe_w, rpe_b, ca, cb,
                                                 graph, gbase, ebuf);
    bucket_to_csr<<<dim3(NBK), 256, 0, stream>>>(gbase, ebuf, cnt, sorted_src);
    attn_score<<<dim3(NUNITS), 256, 0, stream>>>(qbuf16, kh, ca, cb,
                                                 cnt, sorted_src, ebufE, invden, qscore);
    attn_out  <<<dim3(NUNITS), 256, 0, stream>>>(vh, cnt, sorted_src,
                                                 ebufE, invden, out, qout);
}

// Round 6
// 182.087 us; speedup vs baseline: 1.4999x; 1.3237x over previous
//
#include <hip/hip_runtime.h>
#include <hip/hip_bf16.h>

#define NN 50000
#define NE 800000
#define PAD 64          // slots per node; P(deg>=64) ~ 0 for Poisson(16)
#define CAB 196         // ca/cb sub-blocks inside role-3
#define NBK 391         // coarse buckets of 128 nodes (391*128 = 50048 >= NN)
#define CAPB 2560       // per-bucket edge capacity (mean 2048, +11 sigma)
#define GB_STRIDE 32    // gbase padded 1 counter / 128B line

typedef _Float16 fp16x8 __attribute__((ext_vector_type(8)));
typedef _Float16 half2 __attribute__((ext_vector_type(2)));
typedef __attribute__((ext_vector_type(8))) unsigned short ushort8;  // 16 B
typedef __attribute__((ext_vector_type(4))) float f32x4;

static __device__ __forceinline__ unsigned short f2h(float x) {
    _Float16 h = (_Float16)x;                              // v_cvt_f16_f32 (RNE)
    return __builtin_bit_cast(unsigned short, h);
}
static __device__ __forceinline__ float dot2(half2 a, half2 b, float c) {
#if __has_builtin(__builtin_amdgcn_fdot2)
    return __builtin_amdgcn_fdot2(a, b, c, false);         // v_dot2_f32_f16
#else
    return c + (float)a.x * (float)b.x + (float)a.y * (float)b.y;
#endif
}
static __device__ __forceinline__ half2 h2(unsigned u) {
    return __builtin_bit_cast(half2, u);
}

// ---------------------------------------------------------------------------
// Kernel 1 (fused): QKV GEMM + RPE constants + COARSE edge bucketing.
// Structure = r2 (best known). CHANGE: blockIdx permutation puts roles 0..2
// of the same row-tile bi at dispatch positions with equal (p&7), i.e. the
// same XCD under round-robin dispatch -> the fp32 feat tile is fetched from
// HBM once and L2-hit by the other two roles (r0 FETCH showed feat read 3x).
// Mapping: bx<1536: role=(bx&31)>>3, bi=(bx>>5)*8+(bx&7); tail bx>=1536:
// idx=bx-1536, role=idx/7, bi=384+idx%7. Bijective onto (bi 0..390, role 0..3).
// ---------------------------------------------------------------------------
__global__ __launch_bounds__(256) void qkv_gemm(
    const float* __restrict__ feat, const float* __restrict__ w,
    const float* __restrict__ bias, unsigned short* __restrict__ qbuf16,
    unsigned short* __restrict__ kvbuf,
    const float* __restrict__ coord, const float* __restrict__ rpe_w,
    const float* __restrict__ rpe_b, float* __restrict__ ca,
    float* __restrict__ cb,
    const int* __restrict__ graph, unsigned int* __restrict__ gbase,
    unsigned int* __restrict__ ebuf)
{
    const int t  = threadIdx.x;
    const int bx = blockIdx.x;
    int bi, role;
    if (bx < 1536) {
        int rem = bx & 31;
        role = rem >> 3;
        bi   = (bx >> 5) * 8 + (rem & 7);
    } else {
        int idx = bx - 1536;
        role = idx / 7;
        bi   = 384 + idx - role * 7;
    }

    __shared__ __align__(16) unsigned short Ah[128][40];   // 10 KB
    __shared__ __align__(16) unsigned short Bh[128][40];   // 10 KB

    if (role == 3) {                       // aux path (block-uniform branches only)
        unsigned int* hist  = (unsigned int*)&Ah[0][0];    // [512] used: 0..390
        unsigned int* sbase = hist + 512;                  // [512] used: 0..390
        for (int u = t; u < NBK; u += 256) hist[u] = 0u;
        __syncthreads();

        int dsts[8], srcs[8];
        bool ok[8];
        const int e0 = bi * 2048;
#pragma unroll
        for (int u = 0; u < 8; ++u) {
            int e = e0 + u * 256 + t;
            ok[u] = (e < NE);
            if (ok[u]) { dsts[u] = graph[e]; srcs[u] = graph[NE + e]; }
        }
#pragma unroll
        for (int u = 0; u < 8; ++u)
            if (ok[u]) atomicAdd(&hist[dsts[u] >> 7], 1u); // LDS atomic
        __syncthreads();
        for (int u = t; u < NBK; u += 256) {
            unsigned int c = hist[u];
            unsigned int s = c ? atomicAdd(&gbase[u * GB_STRIDE], c) : 0u;  // padded global
            sbase[u] = s;
            hist[u]  = 0u;                                 // reuse as local rank
        }
        __syncthreads();
#pragma unroll
        for (int u = 0; u < 8; ++u)
            if (ok[u]) {
                int b = dsts[u] >> 7;
                unsigned int pos = sbase[b] + atomicAdd(&hist[b], 1u);
                if (pos < CAPB)
                    ebuf[(size_t)b * CAPB + pos] =
                        ((unsigned int)(dsts[u] & 127) << 16) | (unsigned int)srcs[u];
            }

        if (bi < CAB) {
            __shared__ float s_rw[12];
            __shared__ float s_rb[4];
            if (t < 12) {
                int h = t / 3, p = t % 3;
                float s = 0.f;
                for (int d = 0; d < 32; ++d) s += rpe_w[(h * 32 + d) * 3 + p];
                s_rw[t] = s;
            } else if (t < 16) {
                int h = t - 12;
                float s = 0.f;
                for (int d = 0; d < 32; ++d) s += rpe_b[h * 32 + d];
                s_rb[h] = s;
            }
            __syncthreads();
            int n = bi * 256 + t;
            if (n < NN) {
                float c0 = coord[n * 3 + 0], c1 = coord[n * 3 + 1], c2 = coord[n * 3 + 2];
#pragma unroll
                for (int h = 0; h < 4; ++h) {
                    float a = c0 * s_rw[h * 3 + 0] + c1 * s_rw[h * 3 + 1] + c2 * s_rw[h * 3 + 2];
                    ca[n * 4 + h] = a;
                    cb[n * 4 + h] = a + s_rb[h];
                }
            }
        }
        return;
    }

    const int bm = bi * 128;
    const int bc = role * 128;             // 0=q 1=k 2=v

    const int wave = t >> 6;
    const int lane = t & 63;
    const int wr = wave & 1;
    const int wc = wave >> 1;
    const int qd = lane >> 4;
    const int l15 = lane & 15;

    f32x4 acc[4][4];
#pragma unroll
    for (int i = 0; i < 4; ++i)
#pragma unroll
        for (int j = 0; j < 4; ++j)
            acc[i][j] = (f32x4){0.f, 0.f, 0.f, 0.f};

    for (int ks = 0; ks < 4; ++ks) {
        const int k0 = ks * 32;
        if (ks) __syncthreads();
        // stage 128x32 slabs: load fp32, cvt to fp16 inline, write b128 to LDS
#pragma unroll
        for (int c = 0; c < 2; ++c) {
            int idx = c * 256 + t;          // 0..511
            int r  = idx >> 2;
            int c8 = (idx & 3) * 8;
            int ga = bm + r;
            ushort8 a8 = (ushort8){0,0,0,0,0,0,0,0};
            if (ga < NN) {
                const float* ap = feat + (size_t)ga * 128 + k0 + c8;
                float4 x = *(const float4*)ap;
                float4 y = *(const float4*)(ap + 4);
                a8 = (ushort8){f2h(x.x), f2h(x.y), f2h(x.z), f2h(x.w),
                               f2h(y.x), f2h(y.y), f2h(y.z), f2h(y.w)};
            }
            *(ushort8*)&Ah[r][c8] = a8;
            const float* bp = w + (size_t)(bc + r) * 128 + k0 + c8;
            float4 bx2 = *(const float4*)bp;
            float4 by2 = *(const float4*)(bp + 4);
            *(ushort8*)&Bh[r][c8] = (ushort8){f2h(bx2.x), f2h(bx2.y), f2h(bx2.z), f2h(bx2.w),
                                              f2h(by2.x), f2h(by2.y), f2h(by2.z), f2h(by2.w)};
        }
        __syncthreads();
        fp16x8 af[4];
#pragma unroll
        for (int i = 0; i < 4; ++i)
            af[i] = *(const fp16x8*)&Ah[wr * 64 + 16 * i + l15][qd * 8];
#pragma unroll
        for (int j = 0; j < 4; ++j) {
            fp16x8 bf = *(const fp16x8*)&Bh[wc * 64 + 16 * j + l15][qd * 8];
#pragma unroll
            for (int i = 0; i < 4; ++i)
                acc[i][j] = __builtin_amdgcn_mfma_f32_16x16x32_f16(af[i], bf, acc[i][j], 0, 0, 0);
        }
    }

    float bj[4];
#pragma unroll
    for (int j = 0; j < 4; ++j)
        bj[j] = bias[bc + wc * 64 + 16 * j + l15];

    // ---- epilogue: per i-group (32 rows x 128 cols) LDS transpose ----
    unsigned short* Ct = &Ah[0][0];        // Ct[32][136] fp16, overlays Ah
    const int isQ = (role == 0);
    const int half = (role == 1) ? 0 : 128;
    const int relRowW = wr * 16 + qd * 4;

    for (int i = 0; i < 4; ++i) {
        __syncthreads();                   // prior phase's LDS reads done
#pragma unroll
        for (int j = 0; j < 4; ++j) {
            int col = wc * 64 + 16 * j + l15;
#pragma unroll
            for (int rg = 0; rg < 4; ++rg)
                Ct[(relRowW + rg) * 136 + col] = f2h(acc[i][j][rg] + bj[j]);
        }
        __syncthreads();
#pragma unroll
        for (int p = 0; p < 2; ++p) {
            int linear = p * 256 + t;
            int rr = linear >> 4;          // 0..31
            int cc = linear & 15;          // 16B chunk (8 cols)
            int absRow = bm + 16 * i + rr + ((rr >> 4) * 48);
            if (absRow < NN) {
                ushort8 val = *(const ushort8*)&Ct[rr * 136 + cc * 8];
                if (isQ) *(ushort8*)(qbuf16 + (size_t)absRow * 128 + cc * 8) = val;
                else     *(ushort8*)(kvbuf + (size_t)absRow * 256 + half + cc * 8) = val;
            }
        }
    }
}

// ---------------------------------------------------------------------------
// Kernel 2 (fused): in-LDS CSR build + per-node attention. 4 blocks per
// bucket (quadrants of 32 dst nodes). Block scans its bucket's ebuf region
// (contiguous), slot-assigns its quadrant's edges with LDS atomics into an
// LDS slot table (never touches global sorted_src), then runs the proven
// r2 node_attn body (32 lanes/node, k+v from the 512B kv row, 8x unroll)
// for its 32 nodes in 4 groups of 8. Removes the bucket_to_csr launch and
// the 6.4MB sorted_src global round-trip + RFO.
// ---------------------------------------------------------------------------
__global__ __launch_bounds__(256) void attn_fused(
    const unsigned short* __restrict__ qbuf16, const unsigned short* __restrict__ kvbuf,
    const float* __restrict__ ca, const float* __restrict__ cb,
    const unsigned int* __restrict__ gbase, const unsigned int* __restrict__ ebuf,
    float* __restrict__ out)
{
    __shared__ __align__(16) unsigned short slots[32][64];   // 4 KB
    __shared__ unsigned int ncnt[32];

    const int t    = threadIdx.x;
    const int b    = blockIdx.x >> 2;      // bucket 0..390
    const int quad = blockIdx.x & 3;       // 32-node quadrant

    if (t < 32) ncnt[t] = 0u;
    __syncthreads();

    int total = (int)gbase[b * GB_STRIDE];
    if (total > CAPB) total = CAPB;
    const unsigned int* eb = ebuf + (size_t)b * CAPB;
    for (int i = t; i < total; i += 256) {
        unsigned int e = eb[i];
        int dl = (int)(e >> 16);                           // 0..127
        if ((dl >> 5) == quad) {
            int ldl = dl & 31;
            unsigned int slot = atomicAdd(&ncnt[ldl], 1u); // LDS atomic
            if (slot < PAD) slots[ldl][slot] = (unsigned short)(e & 0xFFFFu);
        }
    }
    __syncthreads();

    const int j  = t & 31;
    const int h  = j >> 3;
    const int j8 = j * 8;
    const int h4 = h * 4;
    const int ln = t >> 5;                 // node-within-group 0..7
    const char* kvp = (const char*)kvbuf;
    const char* cap = (const char*)ca;

    for (int g = 0; g < 4; ++g) {
        const int ldl = g * 8 + ln;
        const int n = b * 128 + quad * 32 + ldl;
        if (n >= NN) continue;
        int d = (int)ncnt[ldl];
        if (d > PAD) d = PAD;
        const unsigned short* sl = &slots[ldl][0];

        const uint2 qv = *(const uint2*)((const char*)qbuf16 + (size_t)n * 256 + j8);
        const half2 qh01 = h2(qv.x);
        const half2 qh23 = h2(qv.y);
        const float cbh = cb[n * 4 + h];

        float4 acc = make_float4(0.f, 0.f, 0.f, 0.f);
        float den = 0.f;

        int i = 0;
        for (; i + 7 < d; i += 8) {
            ushort8 s8 = *(const ushort8*)(sl + i);        // LDS, 16B
            unsigned o[8];
#pragma unroll
            for (int u = 0; u < 8; ++u) o[u] = (unsigned)s8[u] << 9;
            uint2 kk[8], vv[8];
            float aa[8];
#pragma unroll
            for (int u = 0; u < 8; ++u) kk[u] = *(const uint2*)(kvp + o[u] + j8);
#pragma unroll
            for (int u = 0; u < 8; ++u) vv[u] = *(const uint2*)(kvp + o[u] + 256 + j8);
#pragma unroll
            for (int u = 0; u < 8; ++u) aa[u] = *(const float*)(cap + (o[u] >> 5) + h4);
            float p[8];
#pragma unroll
            for (int u = 0; u < 8; ++u)
                p[u] = dot2(qh01, h2(kk[u].x), dot2(qh23, h2(kk[u].y), 0.f));
#pragma unroll
            for (int u = 0; u < 8; ++u) p[u] += __shfl_xor(p[u], 1);
#pragma unroll
            for (int u = 0; u < 8; ++u) p[u] += __shfl_xor(p[u], 2);
#pragma unroll
            for (int u = 0; u < 8; ++u) p[u] += __shfl_xor(p[u], 4);
            float e[8];
#pragma unroll
            for (int u = 0; u < 8; ++u) { e[u] = __expf(p[u] + cbh - aa[u]); den += e[u]; }
#pragma unroll
            for (int u = 0; u < 8; ++u) {
                half2 va = h2(vv[u].x);
                half2 vb = h2(vv[u].y);
                acc.x += e[u] * (float)va.x;
                acc.y += e[u] * (float)va.y;
                acc.z += e[u] * (float)vb.x;
                acc.w += e[u] * (float)vb.y;
            }
        }
        for (; i + 3 < d; i += 4) {
            ushort4 s4 = *(const ushort4*)(sl + i);
            unsigned o0 = (unsigned)s4.x << 9;
            unsigned o1 = (unsigned)s4.y << 9;
            unsigned o2 = (unsigned)s4.z << 9;
            unsigned o3 = (unsigned)s4.w << 9;
            uint2 k0 = *(const uint2*)(kvp + o0 + j8);
            uint2 k1 = *(const uint2*)(kvp + o1 + j8);
            uint2 k2 = *(const uint2*)(kvp + o2 + j8);
            uint2 k3 = *(const uint2*)(kvp + o3 + j8);
            uint2 v0 = *(const uint2*)(kvp + o0 + 256 + j8);
            uint2 v1 = *(const uint2*)(kvp + o1 + 256 + j8);
            uint2 v2 = *(const uint2*)(kvp + o2 + 256 + j8);
            uint2 v3 = *(const uint2*)(kvp + o3 + 256 + j8);
            float a0 = *(const float*)(cap + (o0 >> 5) + h4);
            float a1 = *(const float*)(cap + (o1 >> 5) + h4);
            float a2 = *(const float*)(cap + (o2 >> 5) + h4);
            float a3 = *(const float*)(cap + (o3 >> 5) + h4);

            float p0 = dot2(qh01, h2(k0.x), dot2(qh23, h2(k0.y), 0.f));
            float p1 = dot2(qh01, h2(k1.x), dot2(qh23, h2(k1.y), 0.f));
            float p2 = dot2(qh01, h2(k2.x), dot2(qh23, h2(k2.y), 0.f));
            float p3 = dot2(qh01, h2(k3.x), dot2(qh23, h2(k3.y), 0.f));
            p0 += __shfl_xor(p0, 1); p1 += __shfl_xor(p1, 1);
            p2 += __shfl_xor(p2, 1); p3 += __shfl_xor(p3, 1);
            p0 += __shfl_xor(p0, 2); p1 += __shfl_xor(p1, 2);
            p2 += __shfl_xor(p2, 2); p3 += __shfl_xor(p3, 2);
            p0 += __shfl_xor(p0, 4); p1 += __shfl_xor(p1, 4);
            p2 += __shfl_xor(p2, 4); p3 += __shfl_xor(p3, 4);

            float e0 = __expf(p0 + cbh - a0);
            float e1 = __expf(p1 + cbh - a1);
            float e2 = __expf(p2 + cbh - a2);
            float e3 = __expf(p3 + cbh - a3);
            den += (e0 + e1) + (e2 + e3);
            half2 v0a = h2(v0.x), v0b = h2(v0.y);
            half2 v1a = h2(v1.x), v1b = h2(v1.y);
            half2 v2a = h2(v2.x), v2b = h2(v2.y);
            half2 v3a = h2(v3.x), v3b = h2(v3.y);
            acc.x += e0 * (float)v0a.x + e1 * (float)v1a.x + e2 * (float)v2a.x + e3 * (float)v3a.x;
            acc.y += e0 * (float)v0a.y + e1 * (float)v1a.y + e2 * (float)v2a.y + e3 * (float)v3a.y;
            acc.z += e0 * (float)v0b.x + e1 * (float)v1b.x + e2 * (float)v2b.x + e3 * (float)v3b.x;
            acc.w += e0 * (float)v0b.y + e1 * (float)v1b.y + e2 * (float)v2b.y + e3 * (float)v3b.y;
        }
        for (; i < d; ++i) {
            unsigned o0 = (unsigned)sl[i] << 9;
            uint2 k0 = *(const uint2*)(kvp + o0 + j8);
            uint2 v0 = *(const uint2*)(kvp + o0 + 256 + j8);
            float a0 = *(const float*)(cap + (o0 >> 5) + h4);
            float p0 = dot2(qh01, h2(k0.x), dot2(qh23, h2(k0.y), 0.f));
            p0 += __shfl_xor(p0, 1);
            p0 += __shfl_xor(p0, 2);
            p0 += __shfl_xor(p0, 4);
            float e = __expf(p0 + cbh - a0);
            den += e;
            half2 va = h2(v0.x);
            half2 vb = h2(v0.y);
            acc.x += e * (float)va.x;
            acc.y += e * (float)va.y;
            acc.z += e * (float)vb.x;
            acc.w += e * (float)vb.y;
        }

        float inv = (den > 0.f) ? 1.0f / den : 0.f;
        float4 o = make_float4(acc.x * inv, acc.y * inv, acc.z * inv, acc.w * inv);
        ((float4*)(out + (size_t)n * 128))[j] = o;
    }
}

extern "C" void kernel_launch(void* const* d_in, const int* in_sizes, int n_in,
                              void* d_out, int out_size, void* d_ws, size_t ws_size,
                              hipStream_t stream) {
    const float* feat  = (const float*)d_in[0];
    const float* coord = (const float*)d_in[1];
    const int*   graph = (const int*)d_in[2];
    const float* qkv_w = (const float*)d_in[3];
    const float* qkv_b = (const float*)d_in[4];
    const float* rpe_w = (const float*)d_in[5];
    const float* rpe_b = (const float*)d_in[6];
    float* out = (float*)d_out;

    unsigned short* qbuf16 = (unsigned short*)d_ws;                       // NN x 128 f16   (12.8 MB)
    unsigned short* kvbuf  = qbuf16 + (size_t)NN * 128;                   // NN x 256 f16   (25.6 MB)
    float* ca = (float*)(kvbuf + (size_t)NN * 256);                       // NN x 4         (0.8 MB)
    float* cb = ca + (size_t)NN * 4;                                      // NN x 4         (0.8 MB)
    unsigned int* gbase = (unsigned int*)(cb + (size_t)NN * 4);           // NBK x 32       (50 KB)
    unsigned int* ebuf  = gbase + (size_t)NBK * GB_STRIDE;                // NBK x CAPB     (4.0 MB)

    hipMemsetAsync(gbase, 0, (size_t)NBK * GB_STRIDE * sizeof(unsigned int), stream);

    qkv_gemm  <<<dim3(391 * 4), 256, 0, stream>>>(feat, qkv_w, qkv_b, qbuf16, kvbuf,
                                                  coord, rpe_w, rpe_b, ca, cb,
                                                  graph, gbase, ebuf);
    attn_fused<<<dim3(NBK * 4), 256, 0, stream>>>(qbuf16, kvbuf, ca, cb,
                                                  gbase, ebuf, out);
}